// Round 15
// baseline (94.251 us; speedup 1.0000x reference)
//
#include <hip/hip_runtime.h>
#include <hip/hip_bf16.h>

// Relative (Music-Transformer) causal attention, MI355X gfx950.
// logit[i,j] = q_i·k_j + q_i·Erel[L-1-i+j] + key_len_add[j]; causal softmax; ·V
// fp32 in / fp32 out. Swapped-operand 16x16x32 bf16 MFMA ([key][q] layout).
// R15 = R14 with ONLY the barrier changed: __syncthreads (vmcnt0+lgkm0 drain)
// -> lgkm-only s_barrier, so global prefetches (K/V t+2, E t+1, klv) stay in
// flight across the barrier instead of serializing into every tile's chain.

typedef __attribute__((ext_vector_type(8))) short bf16x8;
typedef __attribute__((ext_vector_type(4))) float f32x4;
typedef unsigned short u16;

#define L_Q 2048
#define S_K 2048
#define N_H 8
#define E_D 64
#define RSTRIDE 512
#define LOG2E 1.44269504088896f

#define QW_OFF 0u
#define KW_OFF (4u << 20)
#define VT_OFF (8u << 20)
#define EW_OFF (12u << 20)                 // needs only ~270 KB (rows to 2111)
#define ML_OFF ((12u << 20) + (512u << 10))    // 2048 splits x 128 f32 = 1 MB
#define OW_OFF ((13u << 20) + (512u << 10))    // 2048 splits x 4096 bf16 = 16.8 MB
#define WS_PACK ((size_t)ML_OFF)
#define WS_FULL ((size_t)OW_OFF + (size_t)2048 * 4096 * 2)   // = 30,932,992 (proven)

// lgkm-only barrier: drain LDS ops (writer-side visibility) but leave global
// loads in flight across s_barrier (avoids the compiler's vmcnt(0) drain).
static __device__ __forceinline__ void barrier_lgkm() {
  asm volatile("s_waitcnt lgkmcnt(0)" ::: "memory");
  __builtin_amdgcn_sched_barrier(0);
  __builtin_amdgcn_s_barrier();
  __builtin_amdgcn_sched_barrier(0);
}

static __device__ __forceinline__ short f2bf(float f) {
  unsigned u = __builtin_bit_cast(unsigned, f);
  u += 0x7fffu + ((u >> 16) & 1u);   // RNE
  return (short)(u >> 16);
}

static __device__ __forceinline__ float bf2f(u16 u) {
  return __builtin_bit_cast(float, ((unsigned)u) << 16);
}

static __device__ __forceinline__ unsigned pk2(float a, float b) {
  return (unsigned)(u16)f2bf(a) | ((unsigned)(u16)f2bf(b) << 16);
}

static __device__ __forceinline__ bf16x8 loadpack8(const float* __restrict__ p, float scale) {
  float4 a = *reinterpret_cast<const float4*>(p);
  float4 b = *reinterpret_cast<const float4*>(p + 4);
  bf16x8 r;
  r[0] = f2bf(a.x * scale); r[1] = f2bf(a.y * scale);
  r[2] = f2bf(a.z * scale); r[3] = f2bf(a.w * scale);
  r[4] = f2bf(b.x * scale); r[5] = f2bf(b.y * scale);
  r[6] = f2bf(b.z * scale); r[7] = f2bf(b.w * scale);
  return r;
}

// ---- prep: Q (scaled by 1/8*log2e) & K -> bf16 [nh][seq][e]; Erel -> bf16 ----
__global__ __launch_bounds__(256)
void pack_qke(const float* __restrict__ Qf, const float* __restrict__ Kf,
              const float* __restrict__ Ef, u16* __restrict__ Qw,
              u16* __restrict__ Kw, u16* __restrict__ Ew) {
  const unsigned u = blockIdx.x * 256 + threadIdx.x;   // one float4 per thread
  if (u < 1048576u) {
    const unsigned v  = u & 524287u;
    const int e  = (v & 15) * 4;
    const int i  = (v >> 4) & 2047;
    const int nh = v >> 15;
    const int n = nh >> 3, h = nh & 7;
    const size_t src = ((size_t)(n * L_Q + i) * N_H + h) * E_D + e;
    const size_t dst = ((size_t)nh * L_Q + i) * E_D + e;
    const bool isQ = u < 524288u;
    float4 x = *reinterpret_cast<const float4*>((isQ ? Qf : Kf) + src);
    const float s = isQ ? 0.125f * LOG2E : 1.0f;
    ushort4 o;
    o.x = (u16)f2bf(x.x * s); o.y = (u16)f2bf(x.y * s);
    o.z = (u16)f2bf(x.z * s); o.w = (u16)f2bf(x.w * s);
    *reinterpret_cast<ushort4*>((isQ ? Qw : Kw) + dst) = o;
  } else {
    const unsigned v = u - 1048576u;                    // Erel
    if (v < 32768u) {
      const size_t idx = (size_t)v * 4;
      float4 x = *reinterpret_cast<const float4*>(Ef + idx);
      ushort4 o;
      o.x = (u16)f2bf(x.x); o.y = (u16)f2bf(x.y);
      o.z = (u16)f2bf(x.z); o.w = (u16)f2bf(x.w);
      *reinterpret_cast<ushort4*>(Ew + idx) = o;
    }
  }
}

// ---- prep: V -> bf16 transposed [nh][d][j] ----
__global__ __launch_bounds__(256)
void pack_vt(const float* __restrict__ Vf, u16* __restrict__ Vtw) {
  __shared__ u16 t[64][72];
  const int j0 = blockIdx.x * 64;
  const int nh = blockIdx.y;
  const int n = nh >> 3, h = nh & 7;
  const int tid = threadIdx.x;
  {
    const int jr = tid >> 2, dg = (tid & 3) * 16;
    const float* src = Vf + ((size_t)(n * L_Q + j0 + jr) * N_H + h) * E_D + dg;
#pragma unroll
    for (int q = 0; q < 4; ++q) {
      float4 x = *reinterpret_cast<const float4*>(src + q * 4);
      t[jr][dg + q * 4 + 0] = (u16)f2bf(x.x);
      t[jr][dg + q * 4 + 1] = (u16)f2bf(x.y);
      t[jr][dg + q * 4 + 2] = (u16)f2bf(x.z);
      t[jr][dg + q * 4 + 3] = (u16)f2bf(x.w);
    }
  }
  __syncthreads();
  {
    const int dr = tid >> 2, jg = (tid & 3) * 16;
    u16 tmp[16];
#pragma unroll
    for (int jj = 0; jj < 16; ++jj) tmp[jj] = t[jg + jj][dr];
    u16* dst = Vtw + ((size_t)nh * E_D + dr) * S_K + j0 + jg;
    *reinterpret_cast<uint4*>(dst)     = *reinterpret_cast<uint4*>(&tmp[0]);
    *reinterpret_cast<uint4*>(dst + 8) = *reinterpret_cast<uint4*>(&tmp[8]);
  }
}

// ---- main: K/V shared LDS dbuf; E direct; lgkm-only barrier; KV-split x4 ----
template <bool SPLIT>
__global__ __launch_bounds__(256, 3)
void relattn_r15(const u16* __restrict__ Qw, const u16* __restrict__ Kw,
                 const u16* __restrict__ Vtw, const u16* __restrict__ Ew,
                 const float* __restrict__ KLp, float* __restrict__ Op,
                 u16* __restrict__ OwP, float* __restrict__ MLp) {
  const int bid = blockIdx.x;
  const int nh = bid & 15;                 // head -> fixed XCD pattern
  const int n = nh >> 3, h = nh & 7;
  const int rest = bid >> 4;
  const int wq64 = SPLIT ? (31 - (rest >> 2))
                         : ((rest < 16) ? (31 - rest) : (rest - 16));
  const int sp = SPLIT ? (rest & 3) : 0;
  const int iw64 = wq64 * 64;
  const int tid = threadIdx.x;
  const int wid = tid >> 6;
  const int lane = tid & 63;
  const int lo = lane & 15, hi = lane >> 4;
  const int iw = iw64 + wid * 16;          // this wave's first q-row
  const int nt = wq64 + 1;
  const int t0 = SPLIT ? ((sp * nt) >> 2) : 0;
  const int t1 = SPLIT ? (((sp + 1) * nt) >> 2) : nt;
  const int s = (wq64 * 16 + nh) * 4 + sp;

  __shared__ u16 Kls[2][64 * 64];          // K tiles, swizzled (chunk ^= row&7)
  __shared__ u16 Vls[2][64 * 64];          // V^T tiles, swizzled
  __shared__ float qe_lds[4][16 * 80];     // per-wave QE spill, stride 80

  if (SPLIT && t0 >= t1) {                 // empty split: neutral partials
    u16* OwH = OwP + (size_t)s * 4096 + wid * 1024 + lane * 4;
    ushort4 z4 = {0, 0, 0, 0};
#pragma unroll
    for (int dt = 0; dt < 4; ++dt)
      *reinterpret_cast<ushort4*>(OwH + dt * 256) = z4;
    if (lane < 16) {
      MLp[s * 128 + wid * 32 + lane] = -1e30f;
      MLp[s * 128 + wid * 32 + 16 + lane] = 0.f;
    }
    return;
  }

  const u16* Kg = Kw + (size_t)nh * S_K * E_D;
  const u16* Vg = Vtw + (size_t)nh * E_D * S_K;
  const float* klq = KLp + (size_t)n * S_K + 4 * hi;
  // E direct-global per-lane base (R6-verified): row = 2032 - iw + j0 + tt*16 + lo
  const u16* epl = Ew + (size_t)(2032 - iw) * E_D + lo * E_D + hi * 8;

  // staging lane coords
  const int srow = lane >> 3;
  const int scc  = lane & 7;
  const int r0 = wid * 8 + srow;           // 0..31
  const int r1 = r0 + 32;                  // 32..63
  const int swc = (scc ^ srow) * 8;        // swizzled 16B-chunk offset (u16 units)
  uint4 stK[2], stV[2];

  auto LOAD_KV = [&](int jj0) {
    stK[0] = *reinterpret_cast<const uint4*>(Kg + (size_t)(jj0 + r0) * E_D + scc * 8);
    stK[1] = *reinterpret_cast<const uint4*>(Kg + (size_t)(jj0 + r1) * E_D + scc * 8);
    stV[0] = *reinterpret_cast<const uint4*>(Vg + (size_t)r0 * S_K + jj0 + scc * 8);
    stV[1] = *reinterpret_cast<const uint4*>(Vg + (size_t)r1 * S_K + jj0 + scc * 8);
  };
  auto WRITE_KV = [&](int bb) {
    *reinterpret_cast<uint4*>(&Kls[bb][r0 * 64 + swc]) = stK[0];
    *reinterpret_cast<uint4*>(&Kls[bb][r1 * 64 + swc]) = stK[1];
    *reinterpret_cast<uint4*>(&Vls[bb][r0 * 64 + swc]) = stV[0];
    *reinterpret_cast<uint4*>(&Vls[bb][r1 * 64 + swc]) = stV[1];
  };

  bf16x8 efc[8];                           // next-tile E subtiles 1..4 x kt
  auto LOAD_EFC = [&](int tt64) {
#pragma unroll
    for (int kt = 0; kt < 2; ++kt)
#pragma unroll
      for (int tt = 1; tt < 5; ++tt)
        efc[kt * 4 + tt - 1] = *reinterpret_cast<const bf16x8*>(
            epl + (size_t)(tt64 * 64 + tt * 16) * E_D + kt * 32);
  };

  // Q fragment (B operand): col=lo -> q-row iw+lo, k=hi*8+e (+32*kt)
  bf16x8 qa[2];
  {
    const u16* qrow = Qw + ((size_t)nh * L_Q + iw + lo) * E_D + hi * 8;
    qa[0] = *reinterpret_cast<const bf16x8*>(qrow);
    qa[1] = *reinterpret_cast<const bf16x8*>(qrow + 32);
  }

  // prologue
  LOAD_KV(t0 * 64);
  WRITE_KV(0);
  if (t0 + 1 < t1) LOAD_KV((t0 + 1) * 64);
  LOAD_EFC(t0);
  barrier_lgkm();

  f32x4 o_acc[4] = {};
  float m_run = -1e30f, l_run = 0.f;
  const float* rb = &qe_lds[wid][lo * 80 + (15 - lo) + 4 * hi];
  const int lsw = lo & 7;
  int b = 0;
  f32x4 qe_carry = {};

  for (int t = t0; t < t1; ++t) {
    const int j0 = t * 64;
    if (t + 1 < t1) WRITE_KV(b ^ 1);
    if (t + 2 < t1) LOAD_KV(j0 + 128);

    // ---- QK^T from swizzled LDS ----
    __builtin_amdgcn_s_setprio(1);
    f32x4 s_acc[4] = {};
#pragma unroll
    for (int kt = 0; kt < 2; ++kt)
#pragma unroll
      for (int ct = 0; ct < 4; ++ct) {
        const bf16x8 kf = *reinterpret_cast<const bf16x8*>(
            &Kls[b][(ct * 16 + lo) * 64 + (((kt * 4 + hi) ^ lsw) * 8)]);
        s_acc[ct] = __builtin_amdgcn_mfma_f32_16x16x32_bf16(kf, qa[kt], s_acc[ct], 0, 0, 0);
      }

    // ---- QE band: subtile 0 = carry (or fresh at t0); 1..4 from prefetched efc ----
    f32x4 qe_acc[5];
    if (t == t0) {
      f32x4 z = {};
      qe_acc[0] = z;
#pragma unroll
      for (int kt = 0; kt < 2; ++kt) {
        const bf16x8 e0 = *reinterpret_cast<const bf16x8*>(
            epl + (size_t)(t0 * 64) * E_D + kt * 32);
        qe_acc[0] = __builtin_amdgcn_mfma_f32_16x16x32_bf16(e0, qa[kt], qe_acc[0], 0, 0, 0);
      }
    } else {
      qe_acc[0] = qe_carry;
    }
#pragma unroll
    for (int tt = 1; tt < 5; ++tt) { f32x4 z = {}; qe_acc[tt] = z; }
#pragma unroll
    for (int kt = 0; kt < 2; ++kt)
#pragma unroll
      for (int tt = 1; tt < 5; ++tt)
        qe_acc[tt] = __builtin_amdgcn_mfma_f32_16x16x32_bf16(efc[kt * 4 + tt - 1], qa[kt],
                                                             qe_acc[tt], 0, 0, 0);
    qe_carry = qe_acc[4];
    __builtin_amdgcn_s_setprio(0);

    if (t + 1 < t1) LOAD_EFC(t + 1);       // stays in flight across the barrier

    // ---- spill QE to per-wave LDS (f32, stride 80) ----
#pragma unroll
    for (int tt = 0; tt < 5; ++tt)
      *reinterpret_cast<f32x4*>(&qe_lds[wid][lo * 80 + tt * 16 + 4 * hi]) = qe_acc[tt];

    float4 klv[4];
#pragma unroll
    for (int ct = 0; ct < 4; ++ct)
      klv[ct] = *reinterpret_cast<const float4*>(klq + j0 + ct * 16);

    // ---- logits: QK + rel (u = key - q + 15) + key_len*log2e; causal mask ----
    const bool maskt = (t == nt - 1);
    const int thr = iw + lo - j0 - 4 * hi;   // mask iff ct*16+g > thr
    float p[4][4];
#pragma unroll
    for (int ct = 0; ct < 4; ++ct) {
      const float k0 = klv[ct].x * LOG2E, k1 = klv[ct].y * LOG2E;
      const float k2 = klv[ct].z * LOG2E, k3 = klv[ct].w * LOG2E;
      p[ct][0] = s_acc[ct][0] + rb[ct * 16 + 0] + k0;
      p[ct][1] = s_acc[ct][1] + rb[ct * 16 + 1] + k1;
      p[ct][2] = s_acc[ct][2] + rb[ct * 16 + 2] + k2;
      p[ct][3] = s_acc[ct][3] + rb[ct * 16 + 3] + k3;
      if (maskt) {
#pragma unroll
        for (int g = 0; g < 4; ++g)
          if (ct * 16 + g > thr) p[ct][g] = -1e30f;
      }
    }

    // ---- online softmax (stats per q=lo, reduced across the 4 hi-groups) ----
    float a0 = fmaxf(fmaxf(p[0][0], p[0][1]), fmaxf(p[0][2], p[0][3]));
    float a1 = fmaxf(fmaxf(p[1][0], p[1][1]), fmaxf(p[1][2], p[1][3]));
    float a2 = fmaxf(fmaxf(p[2][0], p[2][1]), fmaxf(p[2][2], p[2][3]));
    float a3 = fmaxf(fmaxf(p[3][0], p[3][1]), fmaxf(p[3][2], p[3][3]));
    float tmax = fmaxf(fmaxf(a0, a1), fmaxf(a2, a3));
    tmax = fmaxf(tmax, __shfl_xor(tmax, 16));
    tmax = fmaxf(tmax, __shfl_xor(tmax, 32));
    const float mnew = fmaxf(m_run, tmax);
    const float alpha = exp2f(m_run - mnew);
#pragma unroll
    for (int ct = 0; ct < 4; ++ct)
#pragma unroll
      for (int g = 0; g < 4; ++g)
        p[ct][g] = exp2f(p[ct][g] - mnew);
    float s0 = (p[0][0] + p[0][1]) + (p[0][2] + p[0][3]);
    float s1 = (p[1][0] + p[1][1]) + (p[1][2] + p[1][3]);
    float s2 = (p[2][0] + p[2][1]) + (p[2][2] + p[2][3]);
    float s3 = (p[3][0] + p[3][1]) + (p[3][2] + p[3][3]);
    float rs = (s0 + s1) + (s2 + s3);
    rs += __shfl_xor(rs, 16);
    rs += __shfl_xor(rs, 32);
    l_run = l_run * alpha + rs;
    m_run = mnew;

#pragma unroll
    for (int dt = 0; dt < 4; ++dt) o_acc[dt] = o_acc[dt] * alpha;

    // ---- pack P to bf16 (k-perm: e<4 -> key 4hi+e; e>=4 -> key 16+4hi+e-4) ----
    uint4 w0, w1;
    w0.x = pk2(p[0][0], p[0][1]); w0.y = pk2(p[0][2], p[0][3]);
    w0.z = pk2(p[1][0], p[1][1]); w0.w = pk2(p[1][2], p[1][3]);
    w1.x = pk2(p[2][0], p[2][1]); w1.y = pk2(p[2][2], p[2][3]);
    w1.z = pk2(p[3][0], p[3][1]); w1.w = pk2(p[3][2], p[3][3]);
    const bf16x8 pb0 = __builtin_bit_cast(bf16x8, w0);
    const bf16x8 pb1 = __builtin_bit_cast(bf16x8, w1);

    // ---- PV from swizzled V^T LDS ----
    __builtin_amdgcn_s_setprio(1);
#pragma unroll
    for (int kt = 0; kt < 2; ++kt)
#pragma unroll
      for (int dt = 0; dt < 4; ++dt) {
        const int vrow = dt * 16 + lo;
        const int ch = kt * 4 + (hi >> 1);
        const uint2 va2 = *reinterpret_cast<const uint2*>(
            &Vls[b][vrow * 64 + ((ch ^ lsw) * 8) + (hi & 1) * 4]);
        const uint2 vb2 = *reinterpret_cast<const uint2*>(
            &Vls[b][vrow * 64 + (((ch + 2) ^ lsw) * 8) + (hi & 1) * 4]);
        uint4 uw; uw.x = va2.x; uw.y = va2.y; uw.z = vb2.x; uw.w = vb2.y;
        const bf16x8 vf = __builtin_bit_cast(bf16x8, uw);
        o_acc[dt] = __builtin_amdgcn_mfma_f32_16x16x32_bf16(vf, kt ? pb1 : pb0, o_acc[dt], 0, 0, 0);
      }
    __builtin_amdgcn_s_setprio(0);

    // ---- lgkm-only barrier: global prefetches stay in flight ----
    barrier_lgkm();
    b ^= 1;
  }

  // ---- epilogue ----
  if (SPLIT) {
    u16* OwH = OwP + (size_t)s * 4096 + wid * 1024 + lane * 4;
#pragma unroll
    for (int dt = 0; dt < 4; ++dt) {
      ushort4 o4;
      o4.x = (u16)f2bf(o_acc[dt][0]); o4.y = (u16)f2bf(o_acc[dt][1]);
      o4.z = (u16)f2bf(o_acc[dt][2]); o4.w = (u16)f2bf(o_acc[dt][3]);
      *reinterpret_cast<ushort4*>(OwH + dt * 256) = o4;
    }
    if (lane < 16) {
      MLp[s * 128 + wid * 32 + lane] = m_run;
      MLp[s * 128 + wid * 32 + 16 + lane] = l_run;
    }
  } else {
    const float inv = 1.f / l_run;
    float* ob = Op + (size_t)n * L_Q * RSTRIDE + h * E_D + (size_t)(iw + lo) * RSTRIDE;
#pragma unroll
    for (int dt = 0; dt < 4; ++dt) {
      f32x4 o = o_acc[dt] * inv;
      *reinterpret_cast<f32x4*>(ob + dt * 16 + 4 * hi) = o;
    }
  }
}

// ---- combine the four KV-split partials (64 q-rows per block) ----
__global__ __launch_bounds__(256)
void combine4(const u16* __restrict__ Owh, const float* __restrict__ MLp,
              float* __restrict__ Op) {
  const int pair = blockIdx.x;             // wq64*16 + nh, 512 blocks
  const int nh = pair & 15;
  const int wq64 = pair >> 4;
  const int n = nh >> 3, h = nh & 7;
  const int tid = threadIdx.x;
  const int wid = tid >> 6;
  const int lane = tid & 63;
  const int lo = lane & 15, hi = lane >> 4;
  const int sb = pair * 4;

  float m[4], l[4];
#pragma unroll
  for (int i = 0; i < 4; ++i) {
    m[i] = MLp[(sb + i) * 128 + wid * 32 + lo];
    l[i] = MLp[(sb + i) * 128 + wid * 32 + 16 + lo];
  }
  float M = fmaxf(fmaxf(m[0], m[1]), fmaxf(m[2], m[3]));
  float w[4]; float den = 0.f;
#pragma unroll
  for (int i = 0; i < 4; ++i) { w[i] = exp2f(m[i] - M); den += l[i] * w[i]; }
  const float inv = 1.f / den;

  float* ob = Op + (size_t)n * L_Q * RSTRIDE + h * E_D
            + (size_t)(wq64 * 64 + wid * 16 + lo) * RSTRIDE;
#pragma unroll
  for (int dt = 0; dt < 4; ++dt) {
    f32x4 acc = {};
#pragma unroll
    for (int i = 0; i < 4; ++i) {
      const ushort4 v = *reinterpret_cast<const ushort4*>(
          Owh + (size_t)(sb + i) * 4096 + wid * 1024 + dt * 256 + lane * 4);
      acc[0] += w[i] * bf2f(v.x);
      acc[1] += w[i] * bf2f(v.y);
      acc[2] += w[i] * bf2f(v.z);
      acc[3] += w[i] * bf2f(v.w);
    }
    f32x4 o = acc * inv;
    *reinterpret_cast<f32x4*>(ob + dt * 16 + 4 * hi) = o;
  }
}

// ---- fallback (no workspace): R3's verified non-packed kernel ----
__global__ __launch_bounds__(64, 2)
void relattn_fb(const float* __restrict__ Qf, const float* __restrict__ Kf,
                const float* __restrict__ Vf, const float* __restrict__ Ef,
                const float* __restrict__ KLp, float* __restrict__ Op) {
  const int bid = blockIdx.x;
  const int nh = bid & 15;
  const int n = nh >> 3, h = nh & 7;
  const int wq = 127 - (bid >> 4);
  const int iw = wq * 16;
  const int lane = threadIdx.x & 63;
  const int lo = lane & 15, hi = lane >> 4;

  __shared__ u16 p_lds[16 * 72];

  const float* klp = KLp + (size_t)n * S_K;
  float* ob = Op + (size_t)n * L_Q * RSTRIDE + h * E_D;

  bf16x8 qa[2];
  const float* qb = Qf + ((size_t)(n * L_Q + iw + lo) * N_H + h) * E_D + hi * 8;
  qa[0] = loadpack8(qb, 0.125f);
  qa[1] = loadpack8(qb + 32, 0.125f);

  f32x4 o_acc[4] = {};
  float m_run[4], l_run[4];
#pragma unroll
  for (int g = 0; g < 4; ++g) { m_run[g] = -1e30f; l_run[g] = 0.f; }

  const int ntiles = (wq >> 2) + 1;
  for (int t = 0; t < ntiles; ++t) {
    const int j0 = t * 64;
    f32x4 s_acc[4] = {};
#pragma unroll
    for (int kt = 0; kt < 2; ++kt)
#pragma unroll
      for (int ct = 0; ct < 4; ++ct) {
        bf16x8 kf = loadpack8(Kf + ((size_t)(n * S_K + j0 + ct * 16 + lo) * N_H + h) * E_D
                                  + kt * 32 + hi * 8, 1.f);
        s_acc[ct] = __builtin_amdgcn_mfma_f32_16x16x32_bf16(qa[kt], kf, s_acc[ct], 0, 0, 0);
      }
    const int mbase = (L_Q - 1) - (iw + 15) + j0;
    f32x4 qe_acc[5] = {};
#pragma unroll
    for (int kt = 0; kt < 2; ++kt)
#pragma unroll
      for (int tt = 0; tt < 5; ++tt) {
        int mr = mbase + tt * 16 + lo;
        mr = mr > (L_Q - 1) ? (L_Q - 1) : mr;
        bf16x8 ef = loadpack8(Ef + (size_t)mr * E_D + kt * 32 + hi * 8, 1.f);
        qe_acc[tt] = __builtin_amdgcn_mfma_f32_16x16x32_bf16(qa[kt], ef, qe_acc[tt], 0, 0, 0);
      }
    float kladd[4];
#pragma unroll
    for (int ct = 0; ct < 4; ++ct) kladd[ct] = klp[j0 + ct * 16 + lo];
    float sv[4][4];
#pragma unroll
    for (int ct = 0; ct < 4; ++ct) {
      const int jj = ct * 16 + lo;
#pragma unroll
      for (int g = 0; g < 4; ++g) {
        const int r = 4 * hi + g;
        const int u = jj - r + 15;
        const int srcl = (u & 15) | (hi << 4);
        const float a = __shfl(qe_acc[ct][g], srcl);
        const float bq = __shfl(qe_acc[ct + 1][g], srcl);
        const float rel = (lo <= r) ? a : bq;
        float sv2 = s_acc[ct][g] + rel + kladd[ct];
        if (j0 + jj > iw + r) sv2 = -1e9f;
        sv[ct][g] = sv2;
      }
    }
    float alpha[4];
#pragma unroll
    for (int g = 0; g < 4; ++g) {
      float mx = fmaxf(fmaxf(sv[0][g], sv[1][g]), fmaxf(sv[2][g], sv[3][g]));
      mx = fmaxf(mx, __shfl_xor(mx, 1));
      mx = fmaxf(mx, __shfl_xor(mx, 2));
      mx = fmaxf(mx, __shfl_xor(mx, 4));
      mx = fmaxf(mx, __shfl_xor(mx, 8));
      const float mnew = fmaxf(m_run[g], mx);
      const float al = __expf(m_run[g] - mnew);
      float rsv = 0.f;
#pragma unroll
      for (int ct = 0; ct < 4; ++ct) {
        const float pv = __expf(sv[ct][g] - mnew);
        sv[ct][g] = pv;
        rsv += pv;
      }
      rsv += __shfl_xor(rsv, 1);
      rsv += __shfl_xor(rsv, 2);
      rsv += __shfl_xor(rsv, 4);
      rsv += __shfl_xor(rsv, 8);
      l_run[g] = l_run[g] * al + rsv;
      m_run[g] = mnew;
      alpha[g] = al;
    }
#pragma unroll
    for (int dt = 0; dt < 4; ++dt)
#pragma unroll
      for (int g = 0; g < 4; ++g)
        o_acc[dt][g] *= alpha[g];
#pragma unroll
    for (int ct = 0; ct < 4; ++ct)
#pragma unroll
      for (int g = 0; g < 4; ++g)
        p_lds[(4 * hi + g) * 72 + ct * 16 + lo] = (u16)f2bf(sv[ct][g]);
#pragma unroll
    for (int jt = 0; jt < 2; ++jt) {
      const bf16x8 pav = *reinterpret_cast<const bf16x8*>(&p_lds[lo * 72 + jt * 32 + hi * 8]);
#pragma unroll
      for (int dt = 0; dt < 4; ++dt) {
        bf16x8 vf;
        const float* vp = Vf + ((size_t)(n * S_K + j0 + jt * 32 + hi * 8) * N_H + h) * E_D
                            + dt * 16 + lo;
#pragma unroll
        for (int e = 0; e < 8; ++e) vf[e] = f2bf(vp[(size_t)e * RSTRIDE]);
        o_acc[dt] = __builtin_amdgcn_mfma_f32_16x16x32_bf16(pav, vf, o_acc[dt], 0, 0, 0);
      }
    }
  }
  float inv[4];
#pragma unroll
  for (int g = 0; g < 4; ++g) inv[g] = 1.f / l_run[g];
#pragma unroll
  for (int dt = 0; dt < 4; ++dt)
#pragma unroll
    for (int g = 0; g < 4; ++g)
      ob[(size_t)(iw + 4 * hi + g) * RSTRIDE + dt * 16 + lo] = o_acc[dt][g] * inv[g];
}

extern "C" void kernel_launch(void* const* d_in, const int* in_sizes, int n_in,
                              void* d_out, int out_size, void* d_ws, size_t ws_size,
                              hipStream_t stream) {
  const float* Q  = (const float*)d_in[0];
  const float* K  = (const float*)d_in[1];
  const float* V  = (const float*)d_in[2];
  const float* E  = (const float*)d_in[3];
  // d_in[4] = attn_mask_add: exactly the causal 0/-1e9 mask -> applied structurally
  const float* KL = (const float*)d_in[5];
  float* O = (float*)d_out;

  char* ws = (char*)d_ws;
  u16* Qw   = (u16*)(ws + QW_OFF);
  u16* Kw   = (u16*)(ws + KW_OFF);
  u16* Vtw  = (u16*)(ws + VT_OFF);
  u16* Ew   = (u16*)(ws + EW_OFF);
  float* ML = (float*)(ws + ML_OFF);
  u16* Ow   = (u16*)(ws + OW_OFF);

  const bool ws_pack = ws_size >= WS_PACK;
  const bool ws_full = ws_size >= WS_FULL;

  if (ws_pack) {
    hipLaunchKernelGGL(pack_qke, dim3((1048576 + 32768 + 255) / 256), dim3(256), 0, stream,
                       Q, K, E, Qw, Kw, Ew);
    hipLaunchKernelGGL(pack_vt, dim3(32, 16), dim3(256), 0, stream, V, Vtw);
  }
  if (ws_full) {
    hipLaunchKernelGGL((relattn_r15<true>), dim3(2048), dim3(256), 0, stream,
                       Qw, Kw, Vtw, Ew, KL, O, Ow, ML);
    hipLaunchKernelGGL(combine4, dim3(512), dim3(256), 0, stream, Ow, ML, O);
  } else if (ws_pack) {
    hipLaunchKernelGGL((relattn_r15<false>), dim3(512), dim3(256), 0, stream,
                       Qw, Kw, Vtw, Ew, KL, O, Ow, ML);
  } else {
    hipLaunchKernelGGL(relattn_fb, dim3(2048), dim3(64), 0, stream, Q, K, V, E, KL, O);
  }
}

// Round 17
// 85.726 us; speedup vs baseline: 1.0994x; 1.0994x over previous
//
#include <hip/hip_runtime.h>
#include <hip/hip_bf16.h>

// Relative (Music-Transformer) causal attention, MI355X gfx950.
// logit[i,j] = q_i·k_j + q_i·Erel[L-1-i+j] + key_len_add[j]; causal softmax; ·V
// fp32 in / fp32 out. Swapped-operand 16x16x32 bf16 MFMA ([key][q] layout).
// R17 = R16 with the mask-gate fixed: maskt = (j0 + 63 > iw)  (was j0 > iw-48,
// which left key>q logits unmasked for waves with iw%64==48).

typedef __attribute__((ext_vector_type(8))) short bf16x8;
typedef __attribute__((ext_vector_type(4))) float f32x4;
typedef unsigned short u16;

#define L_Q 2048
#define S_K 2048
#define N_H 8
#define E_D 64
#define RSTRIDE 512
#define LOG2E 1.44269504088896f

#define QW_OFF 0u
#define KW_OFF (4u << 20)
#define VT_OFF (8u << 20)
#define EW_OFF (12u << 20)                 // ~280 KB used (rows to 2175; >=2048 poison = masked-only)
#define ML_OFF ((12u << 20) + (512u << 10))    // 1024 splits x 256 f32 = 1 MB
#define OW_OFF ((13u << 20) + (512u << 10))    // 1024 splits x 8192 bf16 = 16.8 MB
#define WS_PACK ((size_t)ML_OFF)
#define WS_FULL ((size_t)OW_OFF + (size_t)1024 * 8192 * 2)   // = 30,932,992 (proven present)

static __device__ __forceinline__ short f2bf(float f) {
  unsigned u = __builtin_bit_cast(unsigned, f);
  u += 0x7fffu + ((u >> 16) & 1u);   // RNE
  return (short)(u >> 16);
}

static __device__ __forceinline__ float bf2f(u16 u) {
  return __builtin_bit_cast(float, ((unsigned)u) << 16);
}

static __device__ __forceinline__ unsigned pk2(float a, float b) {
  return (unsigned)(u16)f2bf(a) | ((unsigned)(u16)f2bf(b) << 16);
}

static __device__ __forceinline__ bf16x8 loadpack8(const float* __restrict__ p, float scale) {
  float4 a = *reinterpret_cast<const float4*>(p);
  float4 b = *reinterpret_cast<const float4*>(p + 4);
  bf16x8 r;
  r[0] = f2bf(a.x * scale); r[1] = f2bf(a.y * scale);
  r[2] = f2bf(a.z * scale); r[3] = f2bf(a.w * scale);
  r[4] = f2bf(b.x * scale); r[5] = f2bf(b.y * scale);
  r[6] = f2bf(b.z * scale); r[7] = f2bf(b.w * scale);
  return r;
}

// ---- prep: Q (scaled by 1/8*log2e) & K -> bf16 [nh][seq][e]; Erel -> bf16 ----
__global__ __launch_bounds__(256)
void pack_qke(const float* __restrict__ Qf, const float* __restrict__ Kf,
              const float* __restrict__ Ef, u16* __restrict__ Qw,
              u16* __restrict__ Kw, u16* __restrict__ Ew) {
  const unsigned u = blockIdx.x * 256 + threadIdx.x;   // one float4 per thread
  if (u < 1048576u) {
    const unsigned v  = u & 524287u;
    const int e  = (v & 15) * 4;
    const int i  = (v >> 4) & 2047;
    const int nh = v >> 15;
    const int n = nh >> 3, h = nh & 7;
    const size_t src = ((size_t)(n * L_Q + i) * N_H + h) * E_D + e;
    const size_t dst = ((size_t)nh * L_Q + i) * E_D + e;
    const bool isQ = u < 524288u;
    float4 x = *reinterpret_cast<const float4*>((isQ ? Qf : Kf) + src);
    const float s = isQ ? 0.125f * LOG2E : 1.0f;
    ushort4 o;
    o.x = (u16)f2bf(x.x * s); o.y = (u16)f2bf(x.y * s);
    o.z = (u16)f2bf(x.z * s); o.w = (u16)f2bf(x.w * s);
    *reinterpret_cast<ushort4*>((isQ ? Qw : Kw) + dst) = o;
  } else {
    const unsigned v = u - 1048576u;                    // Erel
    if (v < 32768u) {
      const size_t idx = (size_t)v * 4;
      float4 x = *reinterpret_cast<const float4*>(Ef + idx);
      ushort4 o;
      o.x = (u16)f2bf(x.x); o.y = (u16)f2bf(x.y);
      o.z = (u16)f2bf(x.z); o.w = (u16)f2bf(x.w);
      *reinterpret_cast<ushort4*>(Ew + idx) = o;
    }
  }
}

// ---- prep: V -> bf16 transposed [nh][d][j] ----
__global__ __launch_bounds__(256)
void pack_vt(const float* __restrict__ Vf, u16* __restrict__ Vtw) {
  __shared__ u16 t[64][72];
  const int j0 = blockIdx.x * 64;
  const int nh = blockIdx.y;
  const int n = nh >> 3, h = nh & 7;
  const int tid = threadIdx.x;
  {
    const int jr = tid >> 2, dg = (tid & 3) * 16;
    const float* src = Vf + ((size_t)(n * L_Q + j0 + jr) * N_H + h) * E_D + dg;
#pragma unroll
    for (int q = 0; q < 4; ++q) {
      float4 x = *reinterpret_cast<const float4*>(src + q * 4);
      t[jr][dg + q * 4 + 0] = (u16)f2bf(x.x);
      t[jr][dg + q * 4 + 1] = (u16)f2bf(x.y);
      t[jr][dg + q * 4 + 2] = (u16)f2bf(x.z);
      t[jr][dg + q * 4 + 3] = (u16)f2bf(x.w);
    }
  }
  __syncthreads();
  {
    const int dr = tid >> 2, jg = (tid & 3) * 16;
    u16 tmp[16];
#pragma unroll
    for (int jj = 0; jj < 16; ++jj) tmp[jj] = t[jg + jj][dr];
    u16* dst = Vtw + ((size_t)nh * E_D + dr) * S_K + j0 + jg;
    *reinterpret_cast<uint4*>(dst)     = *reinterpret_cast<uint4*>(&tmp[0]);
    *reinterpret_cast<uint4*>(dst + 8) = *reinterpret_cast<uint4*>(&tmp[8]);
  }
}

// ---- main: 8-wave blocks (128 q-rows); K/V shared LDS dbuf; E direct ----
template <bool SPLIT>
__global__ __launch_bounds__(512, 4)
void relattn_r17(const u16* __restrict__ Qw, const u16* __restrict__ Kw,
                 const u16* __restrict__ Vtw, const u16* __restrict__ Ew,
                 const float* __restrict__ KLp, float* __restrict__ Op,
                 u16* __restrict__ OwP, float* __restrict__ MLp) {
  const int bid = blockIdx.x;
  const int nh = bid & 15;                 // head -> fixed XCD pattern
  const int n = nh >> 3, h = nh & 7;
  const int rest = bid >> 4;
  const int wq128 = SPLIT ? (15 - (rest >> 2))
                          : ((rest < 8) ? (15 - rest) : (rest - 8));
  const int sp = SPLIT ? (rest & 3) : 0;
  const int iw128 = wq128 * 128;
  const int tid = threadIdx.x;
  const int wid = tid >> 6;                // 0..7
  const int lane = tid & 63;
  const int lo = lane & 15, hi = lane >> 4;
  const int iw = iw128 + wid * 16;         // this wave's first q-row
  const int nt = 2 * wq128 + 2;            // key tiles covering 0..iw128+127
  const int t0 = SPLIT ? ((sp * nt) >> 2) : 0;
  const int t1 = SPLIT ? (((sp + 1) * nt) >> 2) : nt;
  const int s = (wq128 * 16 + nh) * 4 + sp;

  __shared__ u16 Kls[2][64 * 64];          // K tiles, swizzled (chunk ^= row&7)
  __shared__ u16 Vls[2][64 * 64];          // V^T tiles, swizzled
  __shared__ float qe_lds[8][16 * 80];     // per-wave QE spill, stride 80

  if (SPLIT && t0 >= t1) {                 // empty split: neutral partials
    u16* OwH = OwP + (size_t)s * 8192 + wid * 1024 + lane * 4;
    ushort4 z4 = {0, 0, 0, 0};
#pragma unroll
    for (int dt = 0; dt < 4; ++dt)
      *reinterpret_cast<ushort4*>(OwH + dt * 256) = z4;
    if (lane < 16) {
      MLp[s * 256 + wid * 32 + lane] = -1e30f;
      MLp[s * 256 + wid * 32 + 16 + lane] = 0.f;
    }
    return;
  }

  const u16* Kg = Kw + (size_t)nh * S_K * E_D;
  const u16* Vg = Vtw + (size_t)nh * E_D * S_K;
  const float* klq = KLp + (size_t)n * S_K + 4 * hi;
  // E direct-global per-lane base (R6-verified): row = 2032 - iw + j0 + tt*16 + lo
  const u16* epl = Ew + (size_t)(2032 - iw) * E_D + lo * E_D + hi * 8;

  // staging: 8 waves x 8 rows = 64 rows; each lane 1 uint4 of K + 1 of V
  const int srow = lane >> 3;
  const int scc  = lane & 7;
  const int r = wid * 8 + srow;            // 0..63
  const int swc = (scc ^ srow) * 8;        // swizzled 16B-chunk offset (u16 units)
  uint4 stK, stV;

  auto LOAD_KV = [&](int jj0) {
    stK = *reinterpret_cast<const uint4*>(Kg + (size_t)(jj0 + r) * E_D + scc * 8);
    stV = *reinterpret_cast<const uint4*>(Vg + (size_t)r * S_K + jj0 + scc * 8);
  };
  auto WRITE_KV = [&](int bb) {
    *reinterpret_cast<uint4*>(&Kls[bb][r * 64 + swc]) = stK;
    *reinterpret_cast<uint4*>(&Vls[bb][r * 64 + swc]) = stV;
  };

  bf16x8 efc[8];                           // next-tile E subtiles 1..4 x kt
  auto LOAD_EFC = [&](int tt64) {
#pragma unroll
    for (int kt = 0; kt < 2; ++kt)
#pragma unroll
      for (int tt = 1; tt < 5; ++tt)
        efc[kt * 4 + tt - 1] = *reinterpret_cast<const bf16x8*>(
            epl + (size_t)(tt64 * 64 + tt * 16) * E_D + kt * 32);
  };

  // Q fragment (B operand): col=lo -> q-row iw+lo, k=hi*8+e (+32*kt)
  bf16x8 qa[2];
  {
    const u16* qrow = Qw + ((size_t)nh * L_Q + iw + lo) * E_D + hi * 8;
    qa[0] = *reinterpret_cast<const bf16x8*>(qrow);
    qa[1] = *reinterpret_cast<const bf16x8*>(qrow + 32);
  }

  // prologue
  LOAD_KV(t0 * 64);
  WRITE_KV(0);
  if (t0 + 1 < t1) LOAD_KV((t0 + 1) * 64);
  LOAD_EFC(t0);
  __syncthreads();

  f32x4 o_acc[4] = {};
  float m_run = -1e30f, l_run = 0.f;
  const float* rb = &qe_lds[wid][lo * 80 + (15 - lo) + 4 * hi];
  const int lsw = lo & 7;
  int b = 0;
  f32x4 qe_carry = {};

  for (int t = t0; t < t1; ++t) {
    const int j0 = t * 64;
    if (t + 1 < t1) WRITE_KV(b ^ 1);
    if (t + 2 < t1) LOAD_KV(j0 + 128);

    // ---- QK^T from swizzled LDS ----
    __builtin_amdgcn_s_setprio(1);
    f32x4 s_acc[4] = {};
#pragma unroll
    for (int kt = 0; kt < 2; ++kt)
#pragma unroll
      for (int ct = 0; ct < 4; ++ct) {
        const bf16x8 kf = *reinterpret_cast<const bf16x8*>(
            &Kls[b][(ct * 16 + lo) * 64 + (((kt * 4 + hi) ^ lsw) * 8)]);
        s_acc[ct] = __builtin_amdgcn_mfma_f32_16x16x32_bf16(kf, qa[kt], s_acc[ct], 0, 0, 0);
      }

    // ---- QE band: subtile 0 = carry (or fresh at t0); 1..4 from prefetched efc ----
    f32x4 qe_acc[5];
    if (t == t0) {
      f32x4 z = {};
      qe_acc[0] = z;
#pragma unroll
      for (int kt = 0; kt < 2; ++kt) {
        const bf16x8 e0 = *reinterpret_cast<const bf16x8*>(
            epl + (size_t)(t0 * 64) * E_D + kt * 32);
        qe_acc[0] = __builtin_amdgcn_mfma_f32_16x16x32_bf16(e0, qa[kt], qe_acc[0], 0, 0, 0);
      }
    } else {
      qe_acc[0] = qe_carry;
    }
#pragma unroll
    for (int tt = 1; tt < 5; ++tt) { f32x4 z = {}; qe_acc[tt] = z; }
#pragma unroll
    for (int kt = 0; kt < 2; ++kt)
#pragma unroll
      for (int tt = 1; tt < 5; ++tt)
        qe_acc[tt] = __builtin_amdgcn_mfma_f32_16x16x32_bf16(efc[kt * 4 + tt - 1], qa[kt],
                                                             qe_acc[tt], 0, 0, 0);
    qe_carry = qe_acc[4];
    __builtin_amdgcn_s_setprio(0);

    if (t + 1 < t1) LOAD_EFC(t + 1);       // prefetch next tile's E

    // ---- spill QE to per-wave LDS (f32, stride 80) ----
#pragma unroll
    for (int tt = 0; tt < 5; ++tt)
      *reinterpret_cast<f32x4*>(&qe_lds[wid][lo * 80 + tt * 16 + 4 * hi]) = qe_acc[tt];

    float4 klv[4];
#pragma unroll
    for (int ct = 0; ct < 4; ++ct)
      klv[ct] = *reinterpret_cast<const float4*>(klq + j0 + ct * 16);

    // ---- logits: QK + rel (u = key - q + 15) + key_len*log2e; causal mask ----
    // mask needed iff the tile's max key (j0+63) can exceed the wave's min q (iw)
    const bool maskt = (j0 + 63 > iw);     // per-wave uniform, conservative-exact
    const int thr = iw + lo - j0 - 4 * hi; // mask iff ct*16+g > thr  (<=> key > q)
    float p[4][4];
#pragma unroll
    for (int ct = 0; ct < 4; ++ct) {
      const float k0 = klv[ct].x * LOG2E, k1 = klv[ct].y * LOG2E;
      const float k2 = klv[ct].z * LOG2E, k3 = klv[ct].w * LOG2E;
      p[ct][0] = s_acc[ct][0] + rb[ct * 16 + 0] + k0;
      p[ct][1] = s_acc[ct][1] + rb[ct * 16 + 1] + k1;
      p[ct][2] = s_acc[ct][2] + rb[ct * 16 + 2] + k2;
      p[ct][3] = s_acc[ct][3] + rb[ct * 16 + 3] + k3;
      if (maskt) {
#pragma unroll
        for (int g = 0; g < 4; ++g)
          if (ct * 16 + g > thr) p[ct][g] = -1e30f;
      }
    }

    // ---- online softmax (stats per q=lo, reduced across the 4 hi-groups) ----
    float a0 = fmaxf(fmaxf(p[0][0], p[0][1]), fmaxf(p[0][2], p[0][3]));
    float a1 = fmaxf(fmaxf(p[1][0], p[1][1]), fmaxf(p[1][2], p[1][3]));
    float a2 = fmaxf(fmaxf(p[2][0], p[2][1]), fmaxf(p[2][2], p[2][3]));
    float a3 = fmaxf(fmaxf(p[3][0], p[3][1]), fmaxf(p[3][2], p[3][3]));
    float tmax = fmaxf(fmaxf(a0, a1), fmaxf(a2, a3));
    tmax = fmaxf(tmax, __shfl_xor(tmax, 16));
    tmax = fmaxf(tmax, __shfl_xor(tmax, 32));
    const float mnew = fmaxf(m_run, tmax);
    const float alpha = exp2f(m_run - mnew);
#pragma unroll
    for (int ct = 0; ct < 4; ++ct)
#pragma unroll
      for (int g = 0; g < 4; ++g)
        p[ct][g] = exp2f(p[ct][g] - mnew);
    float s0 = (p[0][0] + p[0][1]) + (p[0][2] + p[0][3]);
    float s1 = (p[1][0] + p[1][1]) + (p[1][2] + p[1][3]);
    float s2 = (p[2][0] + p[2][1]) + (p[2][2] + p[2][3]);
    float s3 = (p[3][0] + p[3][1]) + (p[3][2] + p[3][3]);
    float rs = (s0 + s1) + (s2 + s3);
    rs += __shfl_xor(rs, 16);
    rs += __shfl_xor(rs, 32);
    l_run = l_run * alpha + rs;
    m_run = mnew;

#pragma unroll
    for (int dt = 0; dt < 4; ++dt) o_acc[dt] = o_acc[dt] * alpha;

    // ---- pack P to bf16 (k-perm: e<4 -> key 4hi+e; e>=4 -> key 16+4hi+e-4) ----
    uint4 w0, w1;
    w0.x = pk2(p[0][0], p[0][1]); w0.y = pk2(p[0][2], p[0][3]);
    w0.z = pk2(p[1][0], p[1][1]); w0.w = pk2(p[1][2], p[1][3]);
    w1.x = pk2(p[2][0], p[2][1]); w1.y = pk2(p[2][2], p[2][3]);
    w1.z = pk2(p[3][0], p[3][1]); w1.w = pk2(p[3][2], p[3][3]);
    const bf16x8 pb0 = __builtin_bit_cast(bf16x8, w0);
    const bf16x8 pb1 = __builtin_bit_cast(bf16x8, w1);

    // ---- PV from swizzled V^T LDS ----
    __builtin_amdgcn_s_setprio(1);
#pragma unroll
    for (int kt = 0; kt < 2; ++kt)
#pragma unroll
      for (int dt = 0; dt < 4; ++dt) {
        const int vrow = dt * 16 + lo;
        const int ch = kt * 4 + (hi >> 1);
        const uint2 va2 = *reinterpret_cast<const uint2*>(
            &Vls[b][vrow * 64 + ((ch ^ lsw) * 8) + (hi & 1) * 4]);
        const uint2 vb2 = *reinterpret_cast<const uint2*>(
            &Vls[b][vrow * 64 + (((ch + 2) ^ lsw) * 8) + (hi & 1) * 4]);
        uint4 uw; uw.x = va2.x; uw.y = va2.y; uw.z = vb2.x; uw.w = vb2.y;
        const bf16x8 vf = __builtin_bit_cast(bf16x8, uw);
        o_acc[dt] = __builtin_amdgcn_mfma_f32_16x16x32_bf16(vf, kt ? pb1 : pb0, o_acc[dt], 0, 0, 0);
      }
    __builtin_amdgcn_s_setprio(0);

    __syncthreads();
    b ^= 1;
  }

  // ---- epilogue ----
  if (SPLIT) {
    u16* OwH = OwP + (size_t)s * 8192 + wid * 1024 + lane * 4;
#pragma unroll
    for (int dt = 0; dt < 4; ++dt) {
      ushort4 o4;
      o4.x = (u16)f2bf(o_acc[dt][0]); o4.y = (u16)f2bf(o_acc[dt][1]);
      o4.z = (u16)f2bf(o_acc[dt][2]); o4.w = (u16)f2bf(o_acc[dt][3]);
      *reinterpret_cast<ushort4*>(OwH + dt * 256) = o4;
    }
    if (lane < 16) {
      MLp[s * 256 + wid * 32 + lane] = m_run;
      MLp[s * 256 + wid * 32 + 16 + lane] = l_run;
    }
  } else {
    const float inv = 1.f / l_run;
    float* ob = Op + (size_t)n * L_Q * RSTRIDE + h * E_D + (size_t)(iw + lo) * RSTRIDE;
#pragma unroll
    for (int dt = 0; dt < 4; ++dt) {
      f32x4 o = o_acc[dt] * inv;
      *reinterpret_cast<f32x4*>(ob + dt * 16 + 4 * hi) = o;
    }
  }
}

// ---- combine the four KV-split partials (128 q-rows per block) ----
__global__ __launch_bounds__(512)
void combine4(const u16* __restrict__ Owh, const float* __restrict__ MLp,
              float* __restrict__ Op) {
  const int pair = blockIdx.x;             // wq128*16 + nh, 256 blocks
  const int nh = pair & 15;
  const int wq128 = pair >> 4;
  const int n = nh >> 3, h = nh & 7;
  const int tid = threadIdx.x;
  const int wid = tid >> 6;
  const int lane = tid & 63;
  const int lo = lane & 15, hi = lane >> 4;
  const int sb = pair * 4;

  float m[4], l[4];
#pragma unroll
  for (int i = 0; i < 4; ++i) {
    m[i] = MLp[(sb + i) * 256 + wid * 32 + lo];
    l[i] = MLp[(sb + i) * 256 + wid * 32 + 16 + lo];
  }
  float M = fmaxf(fmaxf(m[0], m[1]), fmaxf(m[2], m[3]));
  float w[4]; float den = 0.f;
#pragma unroll
  for (int i = 0; i < 4; ++i) { w[i] = exp2f(m[i] - M); den += l[i] * w[i]; }
  const float inv = 1.f / den;

  float* ob = Op + (size_t)n * L_Q * RSTRIDE + h * E_D
            + (size_t)(wq128 * 128 + wid * 16 + lo) * RSTRIDE;
#pragma unroll
  for (int dt = 0; dt < 4; ++dt) {
    f32x4 acc = {};
#pragma unroll
    for (int i = 0; i < 4; ++i) {
      const ushort4 v = *reinterpret_cast<const ushort4*>(
          Owh + (size_t)(sb + i) * 8192 + wid * 1024 + dt * 256 + lane * 4);
      acc[0] += w[i] * bf2f(v.x);
      acc[1] += w[i] * bf2f(v.y);
      acc[2] += w[i] * bf2f(v.z);
      acc[3] += w[i] * bf2f(v.w);
    }
    f32x4 o = acc * inv;
    *reinterpret_cast<f32x4*>(ob + dt * 16 + 4 * hi) = o;
  }
}

// ---- fallback (no workspace): R3's verified non-packed kernel ----
__global__ __launch_bounds__(64, 2)
void relattn_fb(const float* __restrict__ Qf, const float* __restrict__ Kf,
                const float* __restrict__ Vf, const float* __restrict__ Ef,
                const float* __restrict__ KLp, float* __restrict__ Op) {
  const int bid = blockIdx.x;
  const int nh = bid & 15;
  const int n = nh >> 3, h = nh & 7;
  const int wq = 127 - (bid >> 4);
  const int iw = wq * 16;
  const int lane = threadIdx.x & 63;
  const int lo = lane & 15, hi = lane >> 4;

  __shared__ u16 p_lds[16 * 72];

  const float* klp = KLp + (size_t)n * S_K;
  float* ob = Op + (size_t)n * L_Q * RSTRIDE + h * E_D;

  bf16x8 qa[2];
  const float* qb = Qf + ((size_t)(n * L_Q + iw + lo) * N_H + h) * E_D + hi * 8;
  qa[0] = loadpack8(qb, 0.125f);
  qa[1] = loadpack8(qb + 32, 0.125f);

  f32x4 o_acc[4] = {};
  float m_run[4], l_run[4];
#pragma unroll
  for (int g = 0; g < 4; ++g) { m_run[g] = -1e30f; l_run[g] = 0.f; }

  const int ntiles = (wq >> 2) + 1;
  for (int t = 0; t < ntiles; ++t) {
    const int j0 = t * 64;
    f32x4 s_acc[4] = {};
#pragma unroll
    for (int kt = 0; kt < 2; ++kt)
#pragma unroll
      for (int ct = 0; ct < 4; ++ct) {
        bf16x8 kf = loadpack8(Kf + ((size_t)(n * S_K + j0 + ct * 16 + lo) * N_H + h) * E_D
                                  + kt * 32 + hi * 8, 1.f);
        s_acc[ct] = __builtin_amdgcn_mfma_f32_16x16x32_bf16(qa[kt], kf, s_acc[ct], 0, 0, 0);
      }
    const int mbase = (L_Q - 1) - (iw + 15) + j0;
    f32x4 qe_acc[5] = {};
#pragma unroll
    for (int kt = 0; kt < 2; ++kt)
#pragma unroll
      for (int tt = 0; tt < 5; ++tt) {
        int mr = mbase + tt * 16 + lo;
        mr = mr > (L_Q - 1) ? (L_Q - 1) : mr;
        bf16x8 ef = loadpack8(Ef + (size_t)mr * E_D + kt * 32 + hi * 8, 1.f);
        qe_acc[tt] = __builtin_amdgcn_mfma_f32_16x16x32_bf16(qa[kt], ef, qe_acc[tt], 0, 0, 0);
      }
    float kladd[4];
#pragma unroll
    for (int ct = 0; ct < 4; ++ct) kladd[ct] = klp[j0 + ct * 16 + lo];
    float sv[4][4];
#pragma unroll
    for (int ct = 0; ct < 4; ++ct) {
      const int jj = ct * 16 + lo;
#pragma unroll
      for (int g = 0; g < 4; ++g) {
        const int rr = 4 * hi + g;
        const int u = jj - rr + 15;
        const int srcl = (u & 15) | (hi << 4);
        const float a = __shfl(qe_acc[ct][g], srcl);
        const float bq = __shfl(qe_acc[ct + 1][g], srcl);
        const float rel = (lo <= rr) ? a : bq;
        float sv2 = s_acc[ct][g] + rel + kladd[ct];
        if (j0 + jj > iw + rr) sv2 = -1e9f;
        sv[ct][g] = sv2;
      }
    }
    float alpha[4];
#pragma unroll
    for (int g = 0; g < 4; ++g) {
      float mx = fmaxf(fmaxf(sv[0][g], sv[1][g]), fmaxf(sv[2][g], sv[3][g]));
      mx = fmaxf(mx, __shfl_xor(mx, 1));
      mx = fmaxf(mx, __shfl_xor(mx, 2));
      mx = fmaxf(mx, __shfl_xor(mx, 4));
      mx = fmaxf(mx, __shfl_xor(mx, 8));
      const float mnew = fmaxf(m_run[g], mx);
      const float al = __expf(m_run[g] - mnew);
      float rsv = 0.f;
#pragma unroll
      for (int ct = 0; ct < 4; ++ct) {
        const float pv = __expf(sv[ct][g] - mnew);
        sv[ct][g] = pv;
        rsv += pv;
      }
      rsv += __shfl_xor(rsv, 1);
      rsv += __shfl_xor(rsv, 2);
      rsv += __shfl_xor(rsv, 4);
      rsv += __shfl_xor(rsv, 8);
      l_run[g] = l_run[g] * al + rsv;
      m_run[g] = mnew;
      alpha[g] = al;
    }
#pragma unroll
    for (int dt = 0; dt < 4; ++dt)
#pragma unroll
      for (int g = 0; g < 4; ++g)
        o_acc[dt][g] *= alpha[g];
#pragma unroll
    for (int ct = 0; ct < 4; ++ct)
#pragma unroll
      for (int g = 0; g < 4; ++g)
        p_lds[(4 * hi + g) * 72 + ct * 16 + lo] = (u16)f2bf(sv[ct][g]);
#pragma unroll
    for (int jt = 0; jt < 2; ++jt) {
      const bf16x8 pav = *reinterpret_cast<const bf16x8*>(&p_lds[lo * 72 + jt * 32 + hi * 8]);
#pragma unroll
      for (int dt = 0; dt < 4; ++dt) {
        bf16x8 vf;
        const float* vp = Vf + ((size_t)(n * S_K + j0 + jt * 32 + hi * 8) * N_H + h) * E_D
                            + dt * 16 + lo;
#pragma unroll
        for (int e = 0; e < 8; ++e) vf[e] = f2bf(vp[(size_t)e * RSTRIDE]);
        o_acc[dt] = __builtin_amdgcn_mfma_f32_16x16x32_bf16(pav, vf, o_acc[dt], 0, 0, 0);
      }
    }
  }
  float inv[4];
#pragma unroll
  for (int g = 0; g < 4; ++g) inv[g] = 1.f / l_run[g];
#pragma unroll
  for (int dt = 0; dt < 4; ++dt)
#pragma unroll
    for (int g = 0; g < 4; ++g)
      ob[(size_t)(iw + 4 * hi + g) * RSTRIDE + dt * 16 + lo] = o_acc[dt][g] * inv[g];
}

extern "C" void kernel_launch(void* const* d_in, const int* in_sizes, int n_in,
                              void* d_out, int out_size, void* d_ws, size_t ws_size,
                              hipStream_t stream) {
  const float* Q  = (const float*)d_in[0];
  const float* K  = (const float*)d_in[1];
  const float* V  = (const float*)d_in[2];
  const float* E  = (const float*)d_in[3];
  // d_in[4] = attn_mask_add: exactly the causal 0/-1e9 mask -> applied structurally
  const float* KL = (const float*)d_in[5];
  float* O = (float*)d_out;

  char* ws = (char*)d_ws;
  u16* Qw   = (u16*)(ws + QW_OFF);
  u16* Kw   = (u16*)(ws + KW_OFF);
  u16* Vtw  = (u16*)(ws + VT_OFF);
  u16* Ew   = (u16*)(ws + EW_OFF);
  float* ML = (float*)(ws + ML_OFF);
  u16* Ow   = (u16*)(ws + OW_OFF);

  const bool ws_pack = ws_size >= WS_PACK;
  const bool ws_full = ws_size >= WS_FULL;

  if (ws_pack) {
    hipLaunchKernelGGL(pack_qke, dim3((1048576 + 32768 + 255) / 256), dim3(256), 0, stream,
                       Q, K, E, Qw, Kw, Ew);
    hipLaunchKernelGGL(pack_vt, dim3(32, 16), dim3(256), 0, stream, V, Vtw);
  }
  if (ws_full) {
    hipLaunchKernelGGL((relattn_r17<true>), dim3(1024), dim3(512), 0, stream,
                       Qw, Kw, Vtw, Ew, KL, O, Ow, ML);
    hipLaunchKernelGGL(combine4, dim3(256), dim3(512), 0, stream, Ow, ML, O);
  } else if (ws_pack) {
    hipLaunchKernelGGL((relattn_r17<false>), dim3(256), dim3(512), 0, stream,
                       Qw, Kw, Vtw, Ew, KL, O, Ow, ML);
  } else {
    hipLaunchKernelGGL(relattn_fb, dim3(2048), dim3(64), 0, stream, Q, K, V, E, KL, O);
  }
}